// Round 1
// baseline (1579.868 us; speedup 1.0000x reference)
//
#include <hip/hip_runtime.h>
#include <stdint.h>
#include <math.h>

// Problem constants
#define BB 8
#define HH 16
#define SS 1024
#define DD 128
#define NHEAD (BB*HH)   // 128
#define TQ 128          // q rows per block
#define TK 64           // k cols per tile
#define NKT (SS/TK)     // 16
#define THREADS 256

// mask: 1 bit per (head, q, k) = 128*1024*1024 bits = 2^27 -> 2^22 words
#define MASK_WORDS (NHEAD * SS * (SS/32))   // 4,194,304

// ---------------- threefry2x32, key = (0, 42) -----------------------------
__device__ __forceinline__ uint32_t rotl32(uint32_t v, uint32_t s) {
  return (v << s) | (v >> (32u - s));
}

// partitionable path: x0 = hi(counter) = 0, x1 = lo(counter); bits = o0 ^ o1
__device__ __forceinline__ uint32_t threefry_bits(uint32_t ctr) {
  const uint32_t K0 = 0u, K1 = 42u;
  const uint32_t K2 = K0 ^ K1 ^ 0x1BD11BDAu;
  uint32_t x0 = K0;          // 0 + K0
  uint32_t x1 = ctr + K1;
#define TF_RND(r) { x0 += x1; x1 = rotl32(x1, r); x1 ^= x0; }
  TF_RND(13u) TF_RND(15u) TF_RND(26u) TF_RND(6u)
  x0 += K1; x1 += K2 + 1u;
  TF_RND(17u) TF_RND(29u) TF_RND(16u) TF_RND(24u)
  x0 += K2; x1 += K0 + 2u;
  TF_RND(13u) TF_RND(15u) TF_RND(26u) TF_RND(6u)
  x0 += K0; x1 += K1 + 3u;
  TF_RND(17u) TF_RND(29u) TF_RND(16u) TF_RND(24u)
  x0 += K1; x1 += K2 + 4u;
  TF_RND(13u) TF_RND(15u) TF_RND(26u) TF_RND(6u)
  x0 += K2; x1 += K0 + 5u;
#undef TF_RND
  return x0 ^ x1;
}

// keep = uniform(bits) < 0.9  <=>  (bits>>9) < 0x733333  <=>  bits < 0xE6666600
__global__ __launch_bounds__(256) void pm_maskgen(uint32_t* __restrict__ mask) {
  uint32_t wi = blockIdx.x * 256u + threadIdx.x;
  uint32_t base = wi << 5;
  uint32_t w = 0u;
#pragma unroll 4
  for (int b = 0; b < 32; ++b) {
    uint32_t bits = threefry_bits(base + (uint32_t)b);
    w |= (bits < 0xE6666600u) ? (1u << b) : 0u;
  }
  mask[wi] = w;
}

// ---------------- fused attention (fp32, VALU) -----------------------------
// grid.x = NHEAD * (SS/TQ) = 128*8 = 1024 blocks of 256 threads (4 waves)
// thread (ty,tx) = (tid>>4, tid&15); q rows: ty+16*i (i<8); k cols: tx+16*j (j<4)
__global__ __launch_bounds__(THREADS, 1) void pm_attn(
    const float* __restrict__ Qg, const float* __restrict__ Kg,
    const float* __restrict__ Vg, const float* __restrict__ isf,
    const uint32_t* __restrict__ mask, float* __restrict__ Og)
{
  __shared__ float Qs[TQ * 132];   // 67584 B, stride 132 (bank decorrelation)
  __shared__ float KVs[TK * 132];  // 33792 B, K tile then V tile (serial reuse)
  __shared__ float Ps[TQ * 68];    // 34816 B, P tile [q][k], stride 68

  const int tid = threadIdx.x;
  const int ty = tid >> 4;
  const int tx = tid & 15;
  const int head = blockIdx.x >> 3;
  const int qt = blockIdx.x & 7;
  const int qbase = qt * TQ;

  const size_t hoff = (size_t)head * (SS * DD);
  const float* Qh = Qg + hoff + (size_t)qbase * DD;
  const float* Kh = Kg + hoff;
  const float* Vh = Vg + hoff;
  float* Oh = Og + hoff + (size_t)qbase * DD;

  // ---- stage Q tile (128x128) ----
#pragma unroll
  for (int i = 0; i < 16; ++i) {
    int g = (tid << 2) + (i << 10);
    float4 q4 = *reinterpret_cast<const float4*>(Qh + g);
    *reinterpret_cast<float4*>(&Qs[(g >> 7) * 132 + (g & 127)]) = q4;
  }

  float acc[8][8];
  float mrow[8], lrow[8];
#pragma unroll
  for (int i = 0; i < 8; ++i) {
    mrow[i] = -__builtin_inff();
    lrow[i] = 0.f;
#pragma unroll
    for (int j = 0; j < 8; ++j) acc[i][j] = 0.f;
  }

  // prefetch K tile 0 into registers
  float4 kf[8];
#pragma unroll
  for (int i = 0; i < 8; ++i) {
    int g = (tid << 2) + (i << 10);
    kf[i] = *reinterpret_cast<const float4*>(Kh + g);
  }

  for (int kt = 0; kt < NKT; ++kt) {
    __syncthreads();            // prev PV done reading KVs / Ps
    // commit K tile
#pragma unroll
    for (int i = 0; i < 8; ++i) {
      int g = (tid << 2) + (i << 10);
      *reinterpret_cast<float4*>(&KVs[(g >> 7) * 132 + (g & 127)]) = kf[i];
    }
    __syncthreads();            // K visible

    // prefetch V tile (regs) — hides under QK^T
    float4 vf[8];
#pragma unroll
    for (int i = 0; i < 8; ++i) {
      int g = (tid << 2) + (i << 10);
      vf[i] = *reinterpret_cast<const float4*>(Vh + (size_t)kt * (TK * DD) + g);
    }

    // per-column reciprocal scale (scores / isf[col])
    float rs[4];
#pragma unroll
    for (int j = 0; j < 4; ++j) rs[j] = 1.0f / isf[kt * TK + tx + 16 * j];

    // ---- QK^T: s[8 q][4 k] ----
    float s[8][4];
#pragma unroll
    for (int i = 0; i < 8; ++i)
#pragma unroll
      for (int j = 0; j < 4; ++j) s[i][j] = 0.f;

    for (int d = 0; d < DD; d += 4) {
      float4 q4[8], k4[4];
#pragma unroll
      for (int i = 0; i < 8; ++i)
        q4[i] = *reinterpret_cast<const float4*>(&Qs[(ty + 16 * i) * 132 + d]);
#pragma unroll
      for (int j = 0; j < 4; ++j)
        k4[j] = *reinterpret_cast<const float4*>(&KVs[(tx + 16 * j) * 132 + d]);
#pragma unroll
      for (int i = 0; i < 8; ++i)
#pragma unroll
        for (int j = 0; j < 4; ++j) {
          s[i][j] += q4[i].x * k4[j].x;
          s[i][j] += q4[i].y * k4[j].y;
          s[i][j] += q4[i].z * k4[j].z;
          s[i][j] += q4[i].w * k4[j].w;
        }
    }

    // ---- online softmax + dropout mask + P write ----
#pragma unroll
    for (int i = 0; i < 8; ++i) {
#pragma unroll
      for (int j = 0; j < 4; ++j) s[i][j] *= rs[j];

      float mt = fmaxf(fmaxf(s[i][0], s[i][1]), fmaxf(s[i][2], s[i][3]));
      mt = fmaxf(mt, __shfl_xor(mt, 1, 64));
      mt = fmaxf(mt, __shfl_xor(mt, 2, 64));
      mt = fmaxf(mt, __shfl_xor(mt, 4, 64));
      mt = fmaxf(mt, __shfl_xor(mt, 8, 64));

      float mnew = fmaxf(mrow[i], mt);
      float sf = __expf(mrow[i] - mnew);   // first tile: exp(-inf)=0
      mrow[i] = mnew;
      lrow[i] *= sf;
#pragma unroll
      for (int j = 0; j < 8; ++j) acc[i][j] *= sf;

      float e0 = __expf(s[i][0] - mnew);
      float e1 = __expf(s[i][1] - mnew);
      float e2 = __expf(s[i][2] - mnew);
      float e3 = __expf(s[i][3] - mnew);
      float rsum = (e0 + e1) + (e2 + e3);
      rsum += __shfl_xor(rsum, 1, 64);
      rsum += __shfl_xor(rsum, 2, 64);
      rsum += __shfl_xor(rsum, 4, 64);
      rsum += __shfl_xor(rsum, 8, 64);
      lrow[i] += rsum;

      // dropout mask bits for this row's 4 columns
      int qrow = qbase + ty + 16 * i;
      uint32_t wb = ((uint32_t)head << 15) + ((uint32_t)qrow << 5) + ((uint32_t)kt << 1);
      uint2 ww = *reinterpret_cast<const uint2*>(mask + wb);
      int pr = (ty + 16 * i) * 68;
      Ps[pr + tx]      = ((ww.x >> tx)        & 1u) ? e0 : 0.f;
      Ps[pr + tx + 16] = ((ww.x >> (tx + 16)) & 1u) ? e1 : 0.f;
      Ps[pr + tx + 32] = ((ww.y >> tx)        & 1u) ? e2 : 0.f;
      Ps[pr + tx + 48] = ((ww.y >> (tx + 16)) & 1u) ? e3 : 0.f;
    }

    __syncthreads();            // Ps ready; QK^T done reading KVs
    // commit V tile into KVs
#pragma unroll
    for (int i = 0; i < 8; ++i) {
      int g = (tid << 2) + (i << 10);
      *reinterpret_cast<float4*>(&KVs[(g >> 7) * 132 + (g & 127)]) = vf[i];
    }
    __syncthreads();            // V visible

    // prefetch next K tile — hides under PV
    if (kt < NKT - 1) {
#pragma unroll
      for (int i = 0; i < 8; ++i) {
        int g = (tid << 2) + (i << 10);
        kf[i] = *reinterpret_cast<const float4*>(Kh + (size_t)(kt + 1) * (TK * DD) + g);
      }
    }

    // ---- PV: acc[8 q][8 d] += P[8 q][64 k] * V[64 k][8 d] ----
    for (int k = 0; k < TK; k += 4) {
      float4 p4[8];
#pragma unroll
      for (int i = 0; i < 8; ++i)
        p4[i] = *reinterpret_cast<const float4*>(&Ps[(ty + 16 * i) * 68 + k]);
#pragma unroll
      for (int kk = 0; kk < 4; ++kk) {
        float4 va = *reinterpret_cast<const float4*>(&KVs[(k + kk) * 132 + tx * 8]);
        float4 vb = *reinterpret_cast<const float4*>(&KVs[(k + kk) * 132 + tx * 8 + 4]);
#pragma unroll
        for (int i = 0; i < 8; ++i) {
          float p = (kk == 0) ? p4[i].x : (kk == 1) ? p4[i].y : (kk == 2) ? p4[i].z : p4[i].w;
          acc[i][0] += p * va.x;
          acc[i][1] += p * va.y;
          acc[i][2] += p * va.z;
          acc[i][3] += p * va.w;
          acc[i][4] += p * vb.x;
          acc[i][5] += p * vb.y;
          acc[i][6] += p * vb.z;
          acc[i][7] += p * vb.w;
        }
      }
    }
  }

  // ---- epilogue: out = acc / (0.9 * l) ----
#pragma unroll
  for (int i = 0; i < 8; ++i) {
    float inv = 1.0f / (0.9f * lrow[i]);
    int qrow = ty + 16 * i;
    float4 o1, o2;
    o1.x = acc[i][0] * inv; o1.y = acc[i][1] * inv;
    o1.z = acc[i][2] * inv; o1.w = acc[i][3] * inv;
    o2.x = acc[i][4] * inv; o2.y = acc[i][5] * inv;
    o2.z = acc[i][6] * inv; o2.w = acc[i][7] * inv;
    *reinterpret_cast<float4*>(Oh + qrow * DD + tx * 8) = o1;
    *reinterpret_cast<float4*>(Oh + qrow * DD + tx * 8 + 4) = o2;
  }
}

extern "C" void kernel_launch(void* const* d_in, const int* in_sizes, int n_in,
                              void* d_out, int out_size, void* d_ws, size_t ws_size,
                              hipStream_t stream) {
  const float* q   = (const float*)d_in[0];
  const float* k   = (const float*)d_in[1];
  const float* v   = (const float*)d_in[2];
  const float* isf = (const float*)d_in[3];
  uint32_t* mask = (uint32_t*)d_ws;   // 16 MiB packed dropout mask

  pm_maskgen<<<dim3(MASK_WORDS / 256), dim3(256), 0, stream>>>(mask);
  pm_attn<<<dim3(NHEAD * (SS / TQ)), dim3(THREADS), 0, stream>>>(
      q, k, v, isf, mask, (float*)d_out);
}

// Round 2
// 594.519 us; speedup vs baseline: 2.6574x; 2.6574x over previous
//
#include <hip/hip_runtime.h>
#include <hip/hip_bf16.h>
#include <stdint.h>

#define SS 1024
#define DD 128
#define TQ 128          // q rows per block
#define TK 64           // kv cols per tile
#define NKT (SS/TK)     // 16
#define THREADS 256     // 4 waves
#define NHEAD 128

#define MASK_WORDS (NHEAD * SS * (SS/32))   // 4,194,304 words (16 MiB)

typedef short bf16x8 __attribute__((ext_vector_type(8)));
typedef float f32x4  __attribute__((ext_vector_type(4)));

// ---------------- threefry2x32, key = (0, 42) — verified bit-exact (R1) ----
__device__ __forceinline__ uint32_t rotl32(uint32_t v, uint32_t s) {
  return (v << s) | (v >> (32u - s));
}
__device__ __forceinline__ uint32_t threefry_bits(uint32_t ctr) {
  const uint32_t K0 = 0u, K1 = 42u;
  const uint32_t K2 = K0 ^ K1 ^ 0x1BD11BDAu;
  uint32_t x0 = K0;
  uint32_t x1 = ctr + K1;
#define TF_RND(r) { x0 += x1; x1 = rotl32(x1, r); x1 ^= x0; }
  TF_RND(13u) TF_RND(15u) TF_RND(26u) TF_RND(6u)
  x0 += K1; x1 += K2 + 1u;
  TF_RND(17u) TF_RND(29u) TF_RND(16u) TF_RND(24u)
  x0 += K2; x1 += K0 + 2u;
  TF_RND(13u) TF_RND(15u) TF_RND(26u) TF_RND(6u)
  x0 += K0; x1 += K1 + 3u;
  TF_RND(17u) TF_RND(29u) TF_RND(16u) TF_RND(24u)
  x0 += K1; x1 += K2 + 4u;
  TF_RND(13u) TF_RND(15u) TF_RND(26u) TF_RND(6u)
  x0 += K2; x1 += K0 + 5u;
#undef TF_RND
  return x0 ^ x1;
}

__global__ __launch_bounds__(256) void pm_maskgen(uint32_t* __restrict__ mask) {
  uint32_t wi = blockIdx.x * 256u + threadIdx.x;
  uint32_t base = wi << 5;
  uint32_t w = 0u;
#pragma unroll 4
  for (int b = 0; b < 32; ++b) {
    uint32_t bits = threefry_bits(base + (uint32_t)b);
    w |= (bits < 0xE6666600u) ? (1u << b) : 0u;
  }
  mask[wi] = w;
}

// ---------------- bf16 helpers --------------------------------------------
__device__ __forceinline__ short f2bf(float x) {
  return __builtin_bit_cast(short, __float2bfloat16(x));   // RNE
}
__device__ __forceinline__ float bf2f(short b) {
  return __uint_as_float(((uint32_t)(uint16_t)b) << 16);
}
__device__ __forceinline__ uint32_t pack2(short a, short b) {
  return (uint32_t)(uint16_t)a | ((uint32_t)(uint16_t)b << 16);
}
// split x ~= hi + lo (both bf16)
__device__ __forceinline__ void split2(float x, short& hi, short& lo) {
  hi = f2bf(x);
  lo = f2bf(x - bf2f(hi));
}

#define MFMA16(A, B, C) __builtin_amdgcn_mfma_f32_16x16x32_bf16(A, B, C, 0, 0, 0)

// LDS layout (shorts), 16B-aligned base:
//  phase 1: Qhi[128][136] @0, Qlo[128][136] @17408
//  phase 2: Khi[64][136] @0, Klo[64][136] @8704, Vt[128][72] @17408, Pt[128][72] @26624
#define SMEM_SHORTS 35840

__global__ __launch_bounds__(THREADS, 2) void pm_attn(
    const float* __restrict__ Qg, const float* __restrict__ Kg,
    const float* __restrict__ Vg, const float* __restrict__ isf,
    const uint32_t* __restrict__ mask, float* __restrict__ Og)
{
  __shared__ __align__(16) short smem[SMEM_SHORTS];
  short* const Qhi = smem;
  short* const Qlo = smem + 17408;
  short* const Khi = smem;
  short* const Klo = smem + 8704;
  short* const Vt  = smem + 17408;
  short* const Pt  = smem + 26624;

  const int tid  = threadIdx.x;
  const int lane = tid & 63;
  const int wid  = tid >> 6;       // wave 0..3, owns q rows [wid*32, wid*32+32)
  const int lg   = lane >> 4;      // 16-lane group 0..3
  const int tx   = lane & 15;

  // XCD-aware swizzle: same-head blocks colocate on one XCD (1024 % 8 == 0)
  const int swz   = (blockIdx.x & 7) * 128 + (blockIdx.x >> 3);
  const int head  = swz >> 3;
  const int qbase = (swz & 7) * TQ;

  const size_t hoff = (size_t)head * (SS * DD);
  const float* Qh = Qg + hoff + (size_t)qbase * DD;
  const float* Kh = Kg + hoff;
  const float* Vh = Vg + hoff;
  float*       Oh = Og + hoff + (size_t)qbase * DD;

  // ---- phase 1: stage Q (fp32 -> hi/lo bf16 in LDS), then frags -> VGPRs ----
#pragma unroll
  for (int i = 0; i < 16; ++i) {
    int f = tid * 4 + i * 1024;
    float4 q4 = *(const float4*)(Qh + f);
    int row = f >> 7, col = f & 127;
    short h0, h1, h2, h3, l0, l1, l2, l3;
    split2(q4.x, h0, l0); split2(q4.y, h1, l1);
    split2(q4.z, h2, l2); split2(q4.w, h3, l3);
    uint2 ph = { pack2(h0, h1), pack2(h2, h3) };
    uint2 pl = { pack2(l0, l1), pack2(l2, l3) };
    *(uint2*)&Qhi[row * 136 + col] = ph;
    *(uint2*)&Qlo[row * 136 + col] = pl;
  }
  __syncthreads();

  bf16x8 qhi[2][4], qlo[2][4];
#pragma unroll
  for (int qi = 0; qi < 2; ++qi)
#pragma unroll
    for (int ds = 0; ds < 4; ++ds) {
      int off = (wid * 32 + qi * 16 + tx) * 136 + ds * 32 + lg * 8;
      qhi[qi][ds] = *(const bf16x8*)&Qhi[off];
      qlo[qi][ds] = *(const bf16x8*)&Qlo[off];
    }
  // barrier (a) of kt=0 protects the Q->K LDS region reuse

  f32x4 acc[2][8];
  float mrun[2][4], lrun[2][4];
#pragma unroll
  for (int qi = 0; qi < 2; ++qi)
#pragma unroll
    for (int r = 0; r < 4; ++r) {
      mrun[qi][r] = -1e30f;
      lrun[qi][r] = 0.f;
    }
#pragma unroll
  for (int qi = 0; qi < 2; ++qi)
#pragma unroll
    for (int n = 0; n < 8; ++n)
      acc[qi][n] = (f32x4){0.f, 0.f, 0.f, 0.f};

  const int vd  = tid & 127;        // V-stage: this thread's d row
  const int vk0 = (tid >> 7) * 32;  // and 32-k half

  for (int kt = 0; kt < NKT; ++kt) {
    const float* Kt  = Kh + (size_t)kt * (TK * DD);
    const float* Vtg = Vh + (size_t)kt * (TK * DD);

    __syncthreads();   // (a): prev PV done reading LDS / Q-frag reads done

    // ---- stage K tile: fp32 -> hi/lo bf16 ----
#pragma unroll
    for (int i = 0; i < 8; ++i) {
      int f = tid * 4 + i * 1024;
      float4 k4 = *(const float4*)(Kt + f);
      int row = f >> 7, col = f & 127;
      short h0, h1, h2, h3, l0, l1, l2, l3;
      split2(k4.x, h0, l0); split2(k4.y, h1, l1);
      split2(k4.z, h2, l2); split2(k4.w, h3, l3);
      uint2 ph = { pack2(h0, h1), pack2(h2, h3) };
      uint2 pl = { pack2(l0, l1), pack2(l2, l3) };
      *(uint2*)&Khi[row * 136 + col] = ph;
      *(uint2*)&Klo[row * 136 + col] = pl;
    }
    // ---- stage V tile transposed: Vt[d][k] bf16 ----
    {
      uint32_t vw[16];
#pragma unroll
      for (int j = 0; j < 16; ++j) {
        float a = Vtg[(vk0 + 2 * j) * DD + vd];
        float b = Vtg[(vk0 + 2 * j + 1) * DD + vd];
        vw[j] = pack2(f2bf(a), f2bf(b));
      }
      uint4* dst = (uint4*)&Vt[vd * 72 + vk0];
      dst[0] = (uint4){vw[0],  vw[1],  vw[2],  vw[3]};
      dst[1] = (uint4){vw[4],  vw[5],  vw[6],  vw[7]};
      dst[2] = (uint4){vw[8],  vw[9],  vw[10], vw[11]};
      dst[3] = (uint4){vw[12], vw[13], vw[14], vw[15]};
    }
    __syncthreads();   // (b): K/V tiles visible

    // ---- QK^T: hi*hi + lo*hi + hi*lo (bf16x2 split) ----
    f32x4 sc[2][4];
#pragma unroll
    for (int qi = 0; qi < 2; ++qi)
#pragma unroll
      for (int kj = 0; kj < 4; ++kj)
        sc[qi][kj] = (f32x4){0.f, 0.f, 0.f, 0.f};

#pragma unroll
    for (int ds = 0; ds < 4; ++ds) {
#pragma unroll
      for (int kj = 0; kj < 4; ++kj) {
        int off = (kj * 16 + tx) * 136 + ds * 32 + lg * 8;
        bf16x8 bhi = *(const bf16x8*)&Khi[off];
        bf16x8 blo = *(const bf16x8*)&Klo[off];
#pragma unroll
        for (int qi = 0; qi < 2; ++qi) {
          sc[qi][kj] = MFMA16(qhi[qi][ds], bhi, sc[qi][kj]);
          sc[qi][kj] = MFMA16(qlo[qi][ds], bhi, sc[qi][kj]);
          sc[qi][kj] = MFMA16(qhi[qi][ds], blo, sc[qi][kj]);
        }
      }
    }

    // ---- column scale 1/isf, online softmax, dropout, P write ----
    float rs[4];
#pragma unroll
    for (int kj = 0; kj < 4; ++kj)
      rs[kj] = __builtin_amdgcn_rcpf(isf[kt * 64 + kj * 16 + tx]);

#pragma unroll
    for (int qi = 0; qi < 2; ++qi) {
#pragma unroll
      for (int r = 0; r < 4; ++r) {
        float s0 = sc[qi][0][r] * rs[0];
        float s1 = sc[qi][1][r] * rs[1];
        float s2 = sc[qi][2][r] * rs[2];
        float s3 = sc[qi][3][r] * rs[3];
        float mt = fmaxf(fmaxf(s0, s1), fmaxf(s2, s3));
        mt = fmaxf(mt, __shfl_xor(mt, 1, 64));
        mt = fmaxf(mt, __shfl_xor(mt, 2, 64));
        mt = fmaxf(mt, __shfl_xor(mt, 4, 64));
        mt = fmaxf(mt, __shfl_xor(mt, 8, 64));
        float mold = mrun[qi][r];
        float mnew = fmaxf(mold, mt);
        float corr = __expf(mold - mnew);
        mrun[qi][r] = mnew;
        float e0 = __expf(s0 - mnew);
        float e1 = __expf(s1 - mnew);
        float e2 = __expf(s2 - mnew);
        float e3 = __expf(s3 - mnew);
        float rsum = (e0 + e1) + (e2 + e3);
        rsum += __shfl_xor(rsum, 1, 64);
        rsum += __shfl_xor(rsum, 2, 64);
        rsum += __shfl_xor(rsum, 4, 64);
        rsum += __shfl_xor(rsum, 8, 64);
        lrun[qi][r] = lrun[qi][r] * corr + rsum;
#pragma unroll
        for (int n = 0; n < 8; ++n) acc[qi][n][r] *= corr;

        int lrow = wid * 32 + qi * 16 + lg * 4 + r;       // block-local q row
        int qrow_g = qbase + lrow;                        // head-local q row
        uint2 ww = *(const uint2*)(mask +
            (((uint32_t)head << 15) | ((uint32_t)qrow_g << 5) | (uint32_t)(kt << 1)));
        int prow = lrow * 72;
        Pt[prow + tx]      = ((ww.x >> tx) & 1u)        ? f2bf(e0) : (short)0;
        Pt[prow + 16 + tx] = ((ww.x >> (tx + 16)) & 1u) ? f2bf(e1) : (short)0;
        Pt[prow + 32 + tx] = ((ww.y >> tx) & 1u)        ? f2bf(e2) : (short)0;
        Pt[prow + 48 + tx] = ((ww.y >> (tx + 16)) & 1u) ? f2bf(e3) : (short)0;
      }
    }
    __syncthreads();   // (c): P ready

    // ---- PV: acc[q][d] += P[q][k] * V[k][d] ----
#pragma unroll
    for (int ks = 0; ks < 2; ++ks) {
      bf16x8 pa0 = *(const bf16x8*)&Pt[(wid * 32 + tx) * 72 + ks * 32 + lg * 8];
      bf16x8 pa1 = *(const bf16x8*)&Pt[(wid * 32 + 16 + tx) * 72 + ks * 32 + lg * 8];
#pragma unroll
      for (int n = 0; n < 8; ++n) {
        bf16x8 vb = *(const bf16x8*)&Vt[(n * 16 + tx) * 72 + ks * 32 + lg * 8];
        acc[0][n] = MFMA16(pa0, vb, acc[0][n]);
        acc[1][n] = MFMA16(pa1, vb, acc[1][n]);
      }
    }
  }

  // ---- epilogue: out = acc / (0.9 * l) ----
#pragma unroll
  for (int qi = 0; qi < 2; ++qi)
#pragma unroll
    for (int r = 0; r < 4; ++r) {
      float inv = 1.0f / (0.9f * lrun[qi][r]);
      int qrow = wid * 32 + qi * 16 + lg * 4 + r;
#pragma unroll
      for (int n = 0; n < 8; ++n)
        Oh[qrow * DD + n * 16 + tx] = acc[qi][n][r] * inv;
    }
}

extern "C" void kernel_launch(void* const* d_in, const int* in_sizes, int n_in,
                              void* d_out, int out_size, void* d_ws, size_t ws_size,
                              hipStream_t stream) {
  const float* q   = (const float*)d_in[0];
  const float* k   = (const float*)d_in[1];
  const float* v   = (const float*)d_in[2];
  const float* isf = (const float*)d_in[3];
  uint32_t* mask = (uint32_t*)d_ws;   // 16 MiB packed dropout mask

  pm_maskgen<<<dim3(MASK_WORDS / 256), dim3(256), 0, stream>>>(mask);
  pm_attn<<<dim3(NHEAD * (SS / TQ)), dim3(THREADS), 0, stream>>>(
      q, k, v, isf, mask, (float*)d_out);
}